// Round 1
// baseline (156.898 us; speedup 1.0000x reference)
//
#include <hip/hip_runtime.h>

#define POOL   7
#define RSTRIDE 16.0f
#define IMG_H  128
#define IMG_W  128
#define IMG_C  512

// One block (128 threads) per output pixel position (n, py, px).
// Coordinate math is blockIdx-uniform -> scalar regs; each thread blends one
// float4 of the 512-channel vector (16 B/lane coalesced loads & store).
__global__ __launch_bounds__(128)
void RoiPoolingLayer_22462678958491_kernel(const float* __restrict__ image,
                                           const float* __restrict__ roi,
                                           float* __restrict__ out)
{
    const int b   = blockIdx.x;                 // n*49 + py*7 + px
    const int n   = b / (POOL * POOL);
    const int rem = b - n * (POOL * POOL);
    const int py  = rem / POOL;
    const int px  = rem - py * POOL;

    // RoI scalar math (uniform per block)
    const float x = roi[n * 4 + 0];
    const float y = roi[n * 4 + 1];
    const float w = roi[n * 4 + 2];
    const float h = roi[n * 4 + 3];

    const float r  = rintf((x - 0.5f * w) / RSTRIDE);      // col start
    const float c  = rintf((y - 0.5f * h) / RSTRIDE);      // row start
    const float wq = fmaxf(rintf(w / RSTRIDE), 1.0f);
    const float hq = fmaxf(rintf(h / RSTRIDE), 1.0f);

    // y axis (rows): _axis_coords(c, hq, POOL, H)
    float sy = (((float)py + 0.5f) / (float)POOL) * hq - 0.5f;
    sy = fminf(fmaxf(sy, 0.0f), hq - 1.0f);
    const float fy0 = floorf(sy);
    const float ly  = sy - fy0;
    const float fy1 = fminf(fy0 + 1.0f, hq - 1.0f);
    const int iy0 = (int)fminf(fmaxf(c + fy0, 0.0f), (float)(IMG_H - 1));
    const int iy1 = (int)fminf(fmaxf(c + fy1, 0.0f), (float)(IMG_H - 1));

    // x axis (cols): _axis_coords(r, wq, POOL, W)
    float sx = (((float)px + 0.5f) / (float)POOL) * wq - 0.5f;
    sx = fminf(fmaxf(sx, 0.0f), wq - 1.0f);
    const float fx0 = floorf(sx);
    const float lx  = sx - fx0;
    const float fx1 = fminf(fx0 + 1.0f, wq - 1.0f);
    const int ix0 = (int)fminf(fmaxf(r + fx0, 0.0f), (float)(IMG_W - 1));
    const int ix1 = (int)fminf(fmaxf(r + fx1, 0.0f), (float)(IMG_W - 1));

    const float w00 = (1.0f - ly) * (1.0f - lx);
    const float w01 = (1.0f - ly) * lx;
    const float w10 = ly * (1.0f - lx);
    const float w11 = ly * lx;

    const float4* p00 = (const float4*)(image + ((size_t)iy0 * IMG_W + ix0) * IMG_C);
    const float4* p01 = (const float4*)(image + ((size_t)iy0 * IMG_W + ix1) * IMG_C);
    const float4* p10 = (const float4*)(image + ((size_t)iy1 * IMG_W + ix0) * IMG_C);
    const float4* p11 = (const float4*)(image + ((size_t)iy1 * IMG_W + ix1) * IMG_C);
    float4*       po  = (float4*)(out + (size_t)b * IMG_C);

    const int t = threadIdx.x;          // 0..127, one float4 each (512 ch / 4)
    const float4 a  = p00[t];
    const float4 bb = p01[t];
    const float4 cc = p10[t];
    const float4 dd = p11[t];

    float4 o;
    o.x = w00 * a.x + w01 * bb.x + w10 * cc.x + w11 * dd.x;
    o.y = w00 * a.y + w01 * bb.y + w10 * cc.y + w11 * dd.y;
    o.z = w00 * a.z + w01 * bb.z + w10 * cc.z + w11 * dd.z;
    o.w = w00 * a.w + w01 * bb.w + w10 * cc.w + w11 * dd.w;
    po[t] = o;
}

extern "C" void kernel_launch(void* const* d_in, const int* in_sizes, int n_in,
                              void* d_out, int out_size, void* d_ws, size_t ws_size,
                              hipStream_t stream)
{
    const float* image = (const float*)d_in[0];   // (1,128,128,512) fp32
    const float* roi   = (const float*)d_in[1];   // (N,4) fp32
    float*       out   = (float*)d_out;           // (1,N,7,7,512) fp32

    const int N = in_sizes[1] / 4;                // 1000
    const int blocks = N * POOL * POOL;           // 49000

    RoiPoolingLayer_22462678958491_kernel<<<blocks, 128, 0, stream>>>(image, roi, out);
}

// Round 2
// 150.060 us; speedup vs baseline: 1.0456x; 1.0456x over previous
//
#include <hip/hip_runtime.h>

#define POOL    7
#define RSTRIDE 16.0f
#define IMG_H   128
#define IMG_W   128
#define IMG_C   512
#define C4      (IMG_C / 4)   // float4s per pixel

// One block (128 threads) per output ROW (n, py): 7 px * 512 ch.
// blockIdx is swizzled so all rows of one RoI land on ONE XCD (dispatch is
// round-robin blockIdx%8 -> XCD): each RoI's source region is fetched into a
// single per-XCD L2 instead of up to 8. 28 independent loads per thread give
// the wave deep MLP for latency hiding.
template <bool SWIZZLE>
__global__ __launch_bounds__(128)
void RoiPoolingLayer_22462678958491_kernel(const float* __restrict__ image,
                                           const float* __restrict__ roi,
                                           float* __restrict__ out, int N)
{
    int n, py;
    if (SWIZZLE) {
        // grid = N*7, N%8==0: XCD x = b&7 handles RoIs [x*N/8, (x+1)*N/8)
        const int per   = N >> 3;
        const int xcd   = blockIdx.x & 7;
        const int local = blockIdx.x >> 3;        // 0 .. N*7/8-1
        const int q     = local / POOL;
        n  = xcd * per + q;
        py = local - q * POOL;
    } else {
        n  = blockIdx.x / POOL;
        py = blockIdx.x - n * POOL;
    }

    // RoI scalar math (uniform per block -> SGPRs)
    const float x = roi[n * 4 + 0];
    const float y = roi[n * 4 + 1];
    const float w = roi[n * 4 + 2];
    const float h = roi[n * 4 + 3];

    const float r  = rintf((x - 0.5f * w) / RSTRIDE);   // col start
    const float c  = rintf((y - 0.5f * h) / RSTRIDE);   // row start
    const float wq = fmaxf(rintf(w / RSTRIDE), 1.0f);
    const float hq = fmaxf(rintf(h / RSTRIDE), 1.0f);

    // y axis for this output row
    float sy = (((float)py + 0.5f) / (float)POOL) * hq - 0.5f;
    sy = fminf(fmaxf(sy, 0.0f), hq - 1.0f);
    const float fy0 = floorf(sy);
    const float ly  = sy - fy0;
    const float fy1 = fminf(fy0 + 1.0f, hq - 1.0f);
    const int iy0 = (int)fminf(fmaxf(c + fy0, 0.0f), (float)(IMG_H - 1));
    const int iy1 = (int)fminf(fmaxf(c + fy1, 0.0f), (float)(IMG_H - 1));

    const int t = threadIdx.x;                    // channel group 0..127
    const float4* row0 = (const float4*)(image + (size_t)iy0 * IMG_W * IMG_C) + t;
    const float4* row1 = (const float4*)(image + (size_t)iy1 * IMG_W * IMG_C) + t;
    float4* po = (float4*)(out + ((size_t)n * (POOL * POOL) + (size_t)py * POOL) * IMG_C) + t;

#pragma unroll
    for (int px = 0; px < POOL; ++px) {
        float sx = (((float)px + 0.5f) / (float)POOL) * wq - 0.5f;
        sx = fminf(fmaxf(sx, 0.0f), wq - 1.0f);
        const float fx0 = floorf(sx);
        const float lx  = sx - fx0;
        const float fx1 = fminf(fx0 + 1.0f, wq - 1.0f);
        const int ix0 = (int)fminf(fmaxf(r + fx0, 0.0f), (float)(IMG_W - 1));
        const int ix1 = (int)fminf(fmaxf(r + fx1, 0.0f), (float)(IMG_W - 1));

        const float w00 = (1.0f - ly) * (1.0f - lx);
        const float w01 = (1.0f - ly) * lx;
        const float w10 = ly * (1.0f - lx);
        const float w11 = ly * lx;

        const float4 a  = row0[ix0 * C4];
        const float4 bb = row0[ix1 * C4];
        const float4 cc = row1[ix0 * C4];
        const float4 dd = row1[ix1 * C4];

        float4 o;
        o.x = w00 * a.x + w01 * bb.x + w10 * cc.x + w11 * dd.x;
        o.y = w00 * a.y + w01 * bb.y + w10 * cc.y + w11 * dd.y;
        o.z = w00 * a.z + w01 * bb.z + w10 * cc.z + w11 * dd.z;
        o.w = w00 * a.w + w01 * bb.w + w10 * cc.w + w11 * dd.w;
        po[px * C4] = o;
    }
}

extern "C" void kernel_launch(void* const* d_in, const int* in_sizes, int n_in,
                              void* d_out, int out_size, void* d_ws, size_t ws_size,
                              hipStream_t stream)
{
    const float* image = (const float*)d_in[0];   // (1,128,128,512) fp32
    const float* roi   = (const float*)d_in[1];   // (N,4) fp32
    float*       out   = (float*)d_out;           // (1,N,7,7,512) fp32

    const int N = in_sizes[1] / 4;                // 1000
    const int blocks = N * POOL;                  // 7000 row-blocks

    if ((N & 7) == 0) {
        RoiPoolingLayer_22462678958491_kernel<true><<<blocks, 128, 0, stream>>>(image, roi, out, N);
    } else {
        RoiPoolingLayer_22462678958491_kernel<false><<<blocks, 128, 0, stream>>>(image, roi, out, N);
    }
}